// Round 3
// baseline (421.455 us; speedup 1.0000x reference)
//
#include <hip/hip_runtime.h>
#include <math.h>

typedef float    f32x4  __attribute__((ext_vector_type(4)));
typedef short    bf16x8 __attribute__((ext_vector_type(8)));
typedef _Float16 h16x8  __attribute__((ext_vector_type(8)));

#define NTOT 32768      // samples
#define KCB  1024       // codebook
#define DDIM 256        // dim
#define SPAT 4096
#define ZB   1048576

__device__ __forceinline__ unsigned short f2bf(float f){
    unsigned u = __builtin_bit_cast(unsigned, f);
    u += 0x7fffu + ((u >> 16) & 1u);
    return (unsigned short)(u >> 16);
}

// ---------------- init ----------------
__global__ __launch_bounds__(256) void vq_init(int* __restrict__ counts, float* __restrict__ loss){
    int t = threadIdx.x;
    #pragma unroll
    for (int i = 0; i < 4; ++i) counts[i*256 + t] = 0;
    if (t == 0) loss[0] = 0.0f;
}

// ---------------- prepA: z -> fragment-major bf16 A + invn ----------------
__global__ __launch_bounds__(256) void vq_prepA(const float* __restrict__ z, bf16x8* __restrict__ Ab,
                                                float* __restrict__ invn){
    __shared__ unsigned short lds[256][68];
    __shared__ float sbuf[4][64];
    int tid = threadIdx.x, lane = tid & 63, w = tid >> 6;
    int bid = blockIdx.x;
    int n0 = bid * 64, b = n0 >> 12, s0 = n0 & 4095;
    const float* zb = z + (size_t)b * ZB + s0;
    int col4 = tid & 15;
    float sq0 = 0.f, sq1 = 0.f, sq2 = 0.f, sq3 = 0.f;
    #pragma unroll
    for (int it = 0; it < 16; ++it){
        int c = it*16 + (tid >> 4);
        float4 v = *(const float4*)(zb + (size_t)c * SPAT + col4*4);
        sq0 += v.x*v.x; sq1 += v.y*v.y; sq2 += v.z*v.z; sq3 += v.w*v.w;
        unsigned long long pk = (unsigned long long)f2bf(v.x)
                              | ((unsigned long long)f2bf(v.y) << 16)
                              | ((unsigned long long)f2bf(v.z) << 32)
                              | ((unsigned long long)f2bf(v.w) << 48);
        *(unsigned long long*)&lds[c][col4*4] = pk;
    }
    sq0 += __shfl_xor(sq0,16); sq0 += __shfl_xor(sq0,32);
    sq1 += __shfl_xor(sq1,16); sq1 += __shfl_xor(sq1,32);
    sq2 += __shfl_xor(sq2,16); sq2 += __shfl_xor(sq2,32);
    sq3 += __shfl_xor(sq3,16); sq3 += __shfl_xor(sq3,32);
    if (lane < 16){
        sbuf[w][lane*4+0] = sq0; sbuf[w][lane*4+1] = sq1;
        sbuf[w][lane*4+2] = sq2; sbuf[w][lane*4+3] = sq3;
    }
    __syncthreads();
    if (tid < 64){
        float t = sbuf[0][tid] + sbuf[1][tid] + sbuf[2][tid] + sbuf[3][tid];
        invn[n0 + tid] = 1.0f / fmaxf(sqrtf(t), 1e-12f);
    }
    #pragma unroll
    for (int i = 0; i < 8; ++i){
        int x = i*4 + (tid >> 6);
        int cc = x & 7, g = x >> 3;
        int srow = g*16 + (lane & 15);
        int cbase = cc*32 + (lane >> 4)*8;
        bf16x8 fr;
        #pragma unroll
        for (int j = 0; j < 8; ++j) fr[j] = (short)lds[cbase + j][srow];
        Ab[(size_t)bid*2048 + i*256 + tid] = fr;
    }
}

// ---------------- prepB: W -> fragment-major bf16 B ----------------
__global__ __launch_bounds__(256) void vq_prepB(const float* __restrict__ W, bf16x8* __restrict__ Bb){
    int slot = blockIdx.x*256 + threadIdx.x;
    int l = slot & 63, x = slot >> 6;
    int cc = x & 7, kg = x >> 3;
    int krow = kg*16 + (l & 15);
    int cbase = cc*32 + (l >> 4)*8;
    const float* wp = W + (size_t)krow*DDIM + cbase;
    float4 v0 = *(const float4*)wp, v1 = *(const float4*)(wp + 4);
    bf16x8 fr;
    fr[0] = (short)f2bf(v0.x); fr[1] = (short)f2bf(v0.y);
    fr[2] = (short)f2bf(v0.z); fr[3] = (short)f2bf(v0.w);
    fr[4] = (short)f2bf(v1.x); fr[5] = (short)f2bf(v1.y);
    fr[6] = (short)f2bf(v1.z); fr[7] = (short)f2bf(v1.w);
    Bb[slot] = fr;
}

// ---------------- MFMA GEMM: Sh[n][k] = f16(exp(10*L)), + colsum(E) partials ----------------
__global__ __launch_bounds__(256) void vq_gemm(const bf16x8* __restrict__ Ab, const bf16x8* __restrict__ Bb,
                                               const float* __restrict__ invn, _Float16* __restrict__ Sh,
                                               float* __restrict__ P1){
    __shared__ float Rsh[128];
    int tid = threadIdx.x, lane = tid & 63, w = tid >> 6;
    int wm = w >> 1, wn = w & 1;
    int bk = blockIdx.x, bm = blockIdx.y;
    if (tid < 128) Rsh[tid] = 0.0f;
    const bf16x8* Ap = Ab + (size_t)(bm*8 + wm*4)*512 + lane;
    const bf16x8* Bp = Bb + (size_t)(bk*8 + wn*4)*512 + lane;
    f32x4 zero4 = {0.f, 0.f, 0.f, 0.f};
    f32x4 acc[4][4];
    #pragma unroll
    for (int i = 0; i < 4; ++i)
        #pragma unroll
        for (int j = 0; j < 4; ++j) acc[i][j] = zero4;
    bf16x8 aF[2][4], bF[2][4];
    #pragma unroll
    for (int i = 0; i < 4; ++i){ aF[0][i] = Ap[i*512]; bF[0][i] = Bp[i*512]; }
    #pragma unroll
    for (int cc = 0; cc < 8; ++cc){
        int cur = cc & 1, nxt = cur ^ 1;
        if (cc < 7){
            #pragma unroll
            for (int i = 0; i < 4; ++i){
                aF[nxt][i] = Ap[i*512 + (cc+1)*64];
                bF[nxt][i] = Bp[i*512 + (cc+1)*64];
            }
        }
        #pragma unroll
        for (int i = 0; i < 4; ++i)
            #pragma unroll
            for (int j = 0; j < 4; ++j)
                acc[i][j] = __builtin_amdgcn_mfma_f32_16x16x32_bf16(aF[cur][i], bF[cur][j], acc[i][j], 0, 0, 0);
    }
    float invr[4][4];
    int rbase = bm*128 + wm*64 + (lane >> 4)*4;
    #pragma unroll
    for (int i = 0; i < 4; ++i)
        #pragma unroll
        for (int r = 0; r < 4; ++r) invr[i][r] = invn[rbase + i*16 + r];
    int cbase = bk*128 + wn*64 + (lane & 15);
    float cs[4] = {0.f, 0.f, 0.f, 0.f};
    #pragma unroll
    for (int j = 0; j < 4; ++j){
        #pragma unroll
        for (int i = 0; i < 4; ++i){
            #pragma unroll
            for (int r = 0; r < 4; ++r){
                float val = acc[i][j][r] * invr[i][r];
                _Float16 vh = (_Float16)__expf(val * 10.0f);   // S = exp(L/T)
                float Sf = (float)vh;
                cs[j] += Sf * Sf;                               // E = S^2
                Sh[(size_t)(rbase + i*16 + r)*KCB + cbase + j*16] = vh;
            }
        }
        cs[j] += __shfl_xor(cs[j], 16);
        cs[j] += __shfl_xor(cs[j], 32);
    }
    __syncthreads();
    if (lane < 16){
        #pragma unroll
        for (int j = 0; j < 4; ++j) atomicAdd(&Rsh[wn*64 + j*16 + lane], cs[j]);
    }
    __syncthreads();
    if (tid < 128) P1[(size_t)bm*KCB + bk*128 + tid] = Rsh[tid];
}

// ---------------- reduce: a[k] = 1/(1024 * sum_rows P[r][k]) ----------------
__global__ __launch_bounds__(512) void vq_reduce(const float* __restrict__ P, int nrows, float* __restrict__ aout){
    __shared__ float red[16][32];
    int tid = threadIdx.x, kl = tid & 31, rg = tid >> 5;
    int k0 = blockIdx.x * 32;
    float s = 0.f;
    for (int r = rg; r < nrows; r += 16) s += P[(size_t)r*KCB + k0 + kl];
    red[rg][kl] = s;
    __syncthreads();
    if (tid < 32){
        float t = 0.f;
        #pragma unroll
        for (int g = 0; g < 16; ++g) t += red[g][tid];
        aout[k0 + tid] = 1.0f / (1024.0f * t);
    }
}

// ---------------- fused col-normalize + next row-sum partials ----------------
__global__ __launch_bounds__(512) void vq_colrow(const _Float16* __restrict__ Sh, const float* __restrict__ avec,
                                                 float* __restrict__ P){
    __shared__ float ash[1024];
    __shared__ float Rsh[1024];
    int tid = threadIdx.x, lane = tid & 63, w = tid >> 6;
    ((float2*)ash)[tid] = ((const float2*)avec)[tid];
    float2 z2; z2.x = 0.f; z2.y = 0.f;
    ((float2*)Rsh)[tid] = z2;
    __syncthreads();
    float aL[16];
    #pragma unroll
    for (int j = 0; j < 8; ++j){ aL[j] = ash[lane*8 + j]; aL[8+j] = ash[512 + lane*8 + j]; }
    int n0 = blockIdx.x*32 + w*4;
    const h16x8* base = (const h16x8*)Sh;
    h16x8 v[4][2];
    #pragma unroll
    for (int r = 0; r < 4; ++r){
        v[r][0] = base[(size_t)(n0+r)*128 + lane];
        v[r][1] = base[(size_t)(n0+r)*128 + 64 + lane];
    }
    float cs[4];
    #pragma unroll
    for (int r = 0; r < 4; ++r){
        float c = 0.f;
        #pragma unroll
        for (int j = 0; j < 8; ++j){
            float f0 = (float)v[r][0][j]; c = fmaf(f0*f0, aL[j],   c);
            float f1 = (float)v[r][1][j]; c = fmaf(f1*f1, aL[8+j], c);
        }
        cs[r] = c;
    }
    #pragma unroll
    for (int m = 1; m < 64; m <<= 1){
        cs[0] += __shfl_xor(cs[0], m);
        cs[1] += __shfl_xor(cs[1], m);
        cs[2] += __shfl_xor(cs[2], m);
        cs[3] += __shfl_xor(cs[3], m);
    }
    float racc[16];
    #pragma unroll
    for (int j = 0; j < 16; ++j) racc[j] = 0.f;
    #pragma unroll
    for (int r = 0; r < 4; ++r){
        float bn = 1.0f / (32768.0f * cs[r]);
        #pragma unroll
        for (int j = 0; j < 8; ++j){
            float f0 = (float)v[r][0][j]; racc[j]   = fmaf(f0*f0, bn, racc[j]);
            float f1 = (float)v[r][1][j]; racc[8+j] = fmaf(f1*f1, bn, racc[8+j]);
        }
    }
    #pragma unroll
    for (int j = 0; j < 8; ++j){
        atomicAdd(&Rsh[lane*8 + j], racc[j]);
        atomicAdd(&Rsh[512 + lane*8 + j], racc[8+j]);
    }
    __syncthreads();
    ((float2*)(P + (size_t)blockIdx.x*KCB))[tid] = ((float2*)Rsh)[tid];
}

// ---------------- final pass: argmax, counts, loss ----------------
__global__ __launch_bounds__(512) void vq_final(const _Float16* __restrict__ Sh, const float* __restrict__ a3,
                                                int* __restrict__ counts, int* __restrict__ idx,
                                                float* __restrict__ loss_acc){
    __shared__ float ash[1024];
    int tid = threadIdx.x, lane = tid & 63, w = tid >> 6;
    ((float2*)ash)[tid] = ((const float2*)a3)[tid];
    __syncthreads();
    float aL[16];
    #pragma unroll
    for (int j = 0; j < 8; ++j){ aL[j] = ash[lane*8 + j]; aL[8+j] = ash[512 + lane*8 + j]; }
    int n0 = blockIdx.x*32 + w*4;
    const h16x8* base = (const h16x8*)Sh;
    h16x8 v[4][2];
    #pragma unroll
    for (int r = 0; r < 4; ++r){
        v[r][0] = base[(size_t)(n0+r)*128 + lane];
        v[r][1] = base[(size_t)(n0+r)*128 + 64 + lane];
    }
    float cs[4], ss[4], bv[4]; int bk[4];
    #pragma unroll
    for (int r = 0; r < 4; ++r){
        float c = 0.f, s = 0.f, b = -1.f; int k = 0;
        #pragma unroll
        for (int j = 0; j < 8; ++j){
            float f0 = (float)v[r][0][j]; float q0 = f0*f0*aL[j];
            s += f0; c += q0; if (q0 > b){ b = q0; k = lane*8 + j; }
            float f1 = (float)v[r][1][j]; float q1 = f1*f1*aL[8+j];
            s += f1; c += q1; if (q1 > b){ b = q1; k = 512 + lane*8 + j; }
        }
        cs[r] = c; ss[r] = s; bv[r] = b; bk[r] = k;
    }
    #pragma unroll
    for (int m = 1; m < 64; m <<= 1){
        #pragma unroll
        for (int r = 0; r < 4; ++r){
            cs[r] += __shfl_xor(cs[r], m);
            ss[r] += __shfl_xor(ss[r], m);
            float ov = __shfl_xor(bv[r], m); int ok = __shfl_xor(bk[r], m);
            if (ov > bv[r] || (ov == bv[r] && ok < bk[r])){ bv[r] = ov; bk[r] = ok; }
        }
    }
    float lw = 0.f;
    #pragma unroll
    for (int r = 0; r < 4; ++r){
        float rs = 1.0f / ss[r], ci = 1.0f / cs[r];
        #pragma unroll
        for (int j = 0; j < 8; ++j){
            float f0 = (float)v[r][0][j]; float q0 = f0*f0*aL[j]*ci;
            lw = fmaf(q0, __logf(fmaf(f0, rs, 1e-6f)), lw);
            float f1 = (float)v[r][1][j]; float q1 = f1*f1*aL[8+j]*ci;
            lw = fmaf(q1, __logf(fmaf(f1, rs, 1e-6f)), lw);
        }
    }
    #pragma unroll
    for (int m = 1; m < 64; m <<= 1) lw += __shfl_xor(lw, m);
    if (lane == 0){
        #pragma unroll
        for (int r = 0; r < 4; ++r){ idx[n0+r] = bk[r]; atomicAdd(&counts[bk[r]], 1); }
        atomicAdd(loss_acc, lw);
    }
}

// ---------------- finalize: loss + unique ----------------
__global__ __launch_bounds__(256) void vq_finalize(const int* __restrict__ counts,
                                                   const float* __restrict__ loss_acc,
                                                   float* __restrict__ out){
    __shared__ int red[256];
    int t = threadIdx.x, c = 0;
    #pragma unroll
    for (int i = 0; i < 4; ++i) c += (counts[i*256 + t] > 0) ? 1 : 0;
    red[t] = c;
    __syncthreads();
    for (int s = 128; s > 0; s >>= 1){
        if (t < s) red[t] += red[t + s];
        __syncthreads();
    }
    if (t == 0){
        out[8388608] = -loss_acc[0] / 33554432.0f;
        out[8388609] = (float)red[0];
    }
}

// ---------------- z_q gather ----------------
__global__ __launch_bounds__(256) void vq_zq(const float* __restrict__ W, const int* __restrict__ idx,
                                             float* __restrict__ out){
    int gid = blockIdx.x*256 + threadIdx.x;
    int o = gid*4;
    int s = o & 4095, rem = o >> 12, c = rem & 255, b = rem >> 8;
    const int4 iv = *(const int4*)(idx + (b << 12) + s);
    float4 ov;
    ov.x = W[(size_t)iv.x*DDIM + c];
    ov.y = W[(size_t)iv.y*DDIM + c];
    ov.z = W[(size_t)iv.z*DDIM + c];
    ov.w = W[(size_t)iv.w*DDIM + c];
    *(float4*)(out + o) = ov;
}

extern "C" void kernel_launch(void* const* d_in, const int* in_sizes, int n_in,
                              void* d_out, int out_size, void* d_ws, size_t ws_size,
                              hipStream_t stream) {
    const float* z = (const float*)d_in[0];
    const float* W = (const float*)d_in[1];
    float* out = (float*)d_out;
    char* ws = (char*)d_ws;

    _Float16* Sh   = (_Float16*)(ws);                       // 67,108,864
    bf16x8*   Ab   = (bf16x8*)(ws + 67108864);              // 16,777,216
    bf16x8*   Bb   = (bf16x8*)(ws + 83886080);              //    524,288
    float*    invn = (float*)(ws + 84410368);               //    131,072
    float*    P1   = (float*)(ws + 84541440);               //  1,048,576
    float*    P    = (float*)(ws + 85590016);               //  4,194,304
    float*    a1   = (float*)(ws + 89784320);
    float*    a2   = (float*)(ws + 89788416);
    float*    a3   = (float*)(ws + 89792512);
    int*      counts = (int*)(ws + 89796608);
    int*      idx    = (int*)(ws + 89800704);
    float*    loss   = (float*)(ws + 89931776);

    vq_init<<<1, 256, 0, stream>>>(counts, loss);
    vq_prepA<<<512, 256, 0, stream>>>(z, Ab, invn);
    vq_prepB<<<128, 256, 0, stream>>>(W, Bb);
    vq_gemm<<<dim3(8, 256), 256, 0, stream>>>(Ab, Bb, invn, Sh, P1);
    vq_reduce<<<32, 512, 0, stream>>>(P1, 256, a1);
    vq_colrow<<<1024, 512, 0, stream>>>(Sh, a1, P);
    vq_reduce<<<32, 512, 0, stream>>>(P, 1024, a2);
    vq_colrow<<<1024, 512, 0, stream>>>(Sh, a2, P);
    vq_reduce<<<32, 512, 0, stream>>>(P, 1024, a3);
    vq_final<<<1024, 512, 0, stream>>>(Sh, a3, counts, idx, loss);
    vq_finalize<<<1, 256, 0, stream>>>(counts, loss, out);
    vq_zq<<<8192, 256, 0, stream>>>(W, idx, out);
}

// Round 4
// 254.760 us; speedup vs baseline: 1.6543x; 1.6543x over previous
//
#include <hip/hip_runtime.h>
#include <math.h>

typedef float    f32x4  __attribute__((ext_vector_type(4)));
typedef short    bf16x8 __attribute__((ext_vector_type(8)));
typedef _Float16 h16x8  __attribute__((ext_vector_type(8)));

#define NTOT 32768
#define KCB  1024
#define DDIM 256
#define SPAT 4096
#define ZB   1048576

__device__ __forceinline__ unsigned short f2bf(float f){
    unsigned u = __builtin_bit_cast(unsigned, f);
    u += 0x7fffu + ((u >> 16) & 1u);
    return (unsigned short)(u >> 16);
}

// ---------------- init ----------------
__global__ __launch_bounds__(256) void vq_init(int* __restrict__ counts, float* __restrict__ loss){
    int t = threadIdx.x;
    #pragma unroll
    for (int i = 0; i < 4; ++i) counts[i*256 + t] = 0;
    if (t == 0) loss[0] = 0.0f;
}

// ---------------- prepA: z -> fragment-major bf16 + invn ----------------
__global__ __launch_bounds__(256) void vq_prepA(const float* __restrict__ z, bf16x8* __restrict__ Ab,
                                                float* __restrict__ invn){
    __shared__ unsigned short lds[256][68];
    __shared__ float sbuf[4][64];
    int tid = threadIdx.x, lane = tid & 63, w = tid >> 6;
    int bid = blockIdx.x;
    int n0 = bid * 64, b = n0 >> 12, s0 = n0 & 4095;
    const float* zb = z + (size_t)b * ZB + s0;
    int col4 = tid & 15;
    float sq0 = 0.f, sq1 = 0.f, sq2 = 0.f, sq3 = 0.f;
    #pragma unroll
    for (int it = 0; it < 16; ++it){
        int c = it*16 + (tid >> 4);
        float4 v = *(const float4*)(zb + (size_t)c * SPAT + col4*4);
        sq0 += v.x*v.x; sq1 += v.y*v.y; sq2 += v.z*v.z; sq3 += v.w*v.w;
        unsigned long long pk = (unsigned long long)f2bf(v.x)
                              | ((unsigned long long)f2bf(v.y) << 16)
                              | ((unsigned long long)f2bf(v.z) << 32)
                              | ((unsigned long long)f2bf(v.w) << 48);
        *(unsigned long long*)&lds[c][col4*4] = pk;
    }
    sq0 += __shfl_xor(sq0,16); sq0 += __shfl_xor(sq0,32);
    sq1 += __shfl_xor(sq1,16); sq1 += __shfl_xor(sq1,32);
    sq2 += __shfl_xor(sq2,16); sq2 += __shfl_xor(sq2,32);
    sq3 += __shfl_xor(sq3,16); sq3 += __shfl_xor(sq3,32);
    if (lane < 16){
        sbuf[w][lane*4+0] = sq0; sbuf[w][lane*4+1] = sq1;
        sbuf[w][lane*4+2] = sq2; sbuf[w][lane*4+3] = sq3;
    }
    __syncthreads();
    if (tid < 64){
        float t = sbuf[0][tid] + sbuf[1][tid] + sbuf[2][tid] + sbuf[3][tid];
        invn[n0 + tid] = 1.0f / fmaxf(sqrtf(t), 1e-12f);
    }
    #pragma unroll
    for (int i = 0; i < 8; ++i){
        int x = i*4 + (tid >> 6);
        int cc = x & 7, g = x >> 3;
        int srow = g*16 + (lane & 15);
        int cbase = cc*32 + (lane >> 4)*8;
        bf16x8 fr;
        #pragma unroll
        for (int j = 0; j < 8; ++j) fr[j] = (short)lds[cbase + j][srow];
        Ab[(size_t)bid*2048 + i*256 + tid] = fr;
    }
}

// ---------------- prepB: W -> fragment-major bf16 ----------------
__global__ __launch_bounds__(256) void vq_prepB(const float* __restrict__ W, bf16x8* __restrict__ Bb){
    int slot = blockIdx.x*256 + threadIdx.x;
    int l = slot & 63, x = slot >> 6;
    int cc = x & 7, kg = x >> 3;
    int krow = kg*16 + (l & 15);
    int cbase = cc*32 + (l >> 4)*8;
    const float* wp = W + (size_t)krow*DDIM + cbase;
    float4 v0 = *(const float4*)wp, v1 = *(const float4*)(wp + 4);
    bf16x8 fr;
    fr[0] = (short)f2bf(v0.x); fr[1] = (short)f2bf(v0.y);
    fr[2] = (short)f2bf(v0.z); fr[3] = (short)f2bf(v0.w);
    fr[4] = (short)f2bf(v1.x); fr[5] = (short)f2bf(v1.y);
    fr[6] = (short)f2bf(v1.z); fr[7] = (short)f2bf(v1.w);
    Bb[slot] = fr;
}

// ---------------- MFMA GEMM (transposed out): ShT[k][n] = f16(exp(10*L)) ----------------
__global__ __launch_bounds__(256) void vq_gemmT(const bf16x8* __restrict__ Ab, const bf16x8* __restrict__ Bb,
                                                const float* __restrict__ invn, _Float16* __restrict__ ShT){
    int tid = threadIdx.x, lane = tid & 63, w = tid >> 6;
    int wm = w >> 1, wn = w & 1;
    int gk = blockIdx.x, gn = blockIdx.y;
    const bf16x8* Wp = Bb + (size_t)(gk*8 + wm*4)*512 + lane;   // codebook frags (A-operand)
    const bf16x8* Zp = Ab + (size_t)(gn*8 + wn*4)*512 + lane;   // sample frags  (B-operand)
    f32x4 zero4 = {0.f, 0.f, 0.f, 0.f};
    f32x4 acc[4][4];
    #pragma unroll
    for (int i = 0; i < 4; ++i)
        #pragma unroll
        for (int j = 0; j < 4; ++j) acc[i][j] = zero4;
    bf16x8 wF[2][4], zF[2][4];
    #pragma unroll
    for (int i = 0; i < 4; ++i){ wF[0][i] = Wp[i*512]; zF[0][i] = Zp[i*512]; }
    #pragma unroll
    for (int cc = 0; cc < 8; ++cc){
        int cur = cc & 1, nxt = cur ^ 1;
        if (cc < 7){
            #pragma unroll
            for (int i = 0; i < 4; ++i){
                wF[nxt][i] = Wp[i*512 + (cc+1)*64];
                zF[nxt][i] = Zp[i*512 + (cc+1)*64];
            }
        }
        #pragma unroll
        for (int i = 0; i < 4; ++i)
            #pragma unroll
            for (int j = 0; j < 4; ++j)
                acc[i][j] = __builtin_amdgcn_mfma_f32_16x16x32_bf16(wF[cur][i], zF[cur][j], acc[i][j], 0, 0, 0);
    }
    // epilogue: rows = codebook k, cols = samples n
    int kbase = gk*128 + wm*64 + (lane >> 4)*4;
    int nbase = gn*128 + wn*64 + (lane & 15);
    float invc[4];
    #pragma unroll
    for (int j = 0; j < 4; ++j) invc[j] = invn[nbase + j*16];
    #pragma unroll
    for (int i = 0; i < 4; ++i)
        #pragma unroll
        for (int j = 0; j < 4; ++j)
            #pragma unroll
            for (int rr = 0; rr < 4; ++rr){
                float val = acc[i][j][rr] * invc[j];
                ShT[(size_t)(kbase + i*16 + rr)*NTOT + nbase + j*16] = (_Float16)__expf(val * 10.0f);
            }
}

// ---------------- row pass: a[k] = 1/(1024 * sum_n S^2 * b[n]) ----------------
__global__ __launch_bounds__(256) void vq_row(const _Float16* __restrict__ ShT, const float* __restrict__ bvec,
                                              int useb, float* __restrict__ aout){
    __shared__ float part[4];
    int tid = threadIdx.x, lane = tid & 63, w = tid >> 6;
    int k = blockIdx.x;
    const h16x8* Sp = (const h16x8*)(ShT + (size_t)k*NTOT) + w*1024 + lane;
    float acc = 0.f;
    if (useb){
        const float4* bp = (const float4*)bvec + w*2048 + lane*2;
        #pragma unroll 4
        for (int it = 0; it < 16; ++it){
            h16x8 s = Sp[it*64];
            float4 b0 = bp[it*128];
            float4 b1 = bp[it*128 + 1];
            float f;
            f = (float)s[0]; acc = fmaf(f*f, b0.x, acc);
            f = (float)s[1]; acc = fmaf(f*f, b0.y, acc);
            f = (float)s[2]; acc = fmaf(f*f, b0.z, acc);
            f = (float)s[3]; acc = fmaf(f*f, b0.w, acc);
            f = (float)s[4]; acc = fmaf(f*f, b1.x, acc);
            f = (float)s[5]; acc = fmaf(f*f, b1.y, acc);
            f = (float)s[6]; acc = fmaf(f*f, b1.z, acc);
            f = (float)s[7]; acc = fmaf(f*f, b1.w, acc);
        }
    } else {
        #pragma unroll 4
        for (int it = 0; it < 16; ++it){
            h16x8 s = Sp[it*64];
            #pragma unroll
            for (int j = 0; j < 8; ++j){ float f = (float)s[j]; acc = fmaf(f, f, acc); }
        }
    }
    #pragma unroll
    for (int m = 1; m < 64; m <<= 1) acc += __shfl_xor(acc, m);
    if (lane == 0) part[w] = acc;
    __syncthreads();
    if (tid == 0) aout[k] = 1.0f / (1024.0f * (part[0] + part[1] + part[2] + part[3]));
}

// ---------------- col pass: b[n] = 1/(32768 * sum_k S^2 * a[k]) ----------------
__global__ __launch_bounds__(512) void vq_col(const _Float16* __restrict__ ShT, const float* __restrict__ avec,
                                              float* __restrict__ bout){
    __shared__ float ash[1024];
    __shared__ float part[8][64];
    int tid = threadIdx.x, lane = tid & 63, w = tid >> 6;
    ((float2*)ash)[tid] = ((const float2*)avec)[tid];
    __syncthreads();
    int n = blockIdx.x*64 + lane;
    const _Float16* Sp = ShT + (size_t)(w*128)*NTOT + n;
    float c = 0.f;
    #pragma unroll 4
    for (int kk = 0; kk < 128; ++kk){
        float S = (float)Sp[(size_t)kk*NTOT];
        c = fmaf(S*S, ash[w*128 + kk], c);
    }
    part[w][lane] = c;
    __syncthreads();
    if (tid < 64){
        float t = 0.f;
        #pragma unroll
        for (int g = 0; g < 8; ++g) t += part[g][tid];
        bout[blockIdx.x*64 + tid] = 1.0f / (32768.0f * t);
    }
}

// ---------------- final: argmax, counts, loss (all lane-local over k) ----------------
__global__ __launch_bounds__(512) void vq_final(const _Float16* __restrict__ ShT, const float* __restrict__ avec,
                                                int* __restrict__ counts, int* __restrict__ idx,
                                                float* __restrict__ loss_acc){
    __shared__ float ash[1024];
    __shared__ float pc[8][64], ps[8][64], pt[8][64], pb[8][64];
    __shared__ int   pkk[8][64];
    int tid = threadIdx.x, lane = tid & 63, w = tid >> 6;
    ((float2*)ash)[tid] = ((const float2*)avec)[tid];
    __syncthreads();
    int n = blockIdx.x*64 + lane;
    const _Float16* Sp = ShT + (size_t)(w*128)*NTOT + n;
    float c = 0.f, ss = 0.f, t = 0.f, bv = -1.f;
    int bk = 0;
    #pragma unroll 4
    for (int kk = 0; kk < 128; ++kk){
        float S = (float)Sp[(size_t)kk*NTOT];
        float q = S*S*ash[w*128 + kk];
        c += q; ss += S;
        t = fmaf(q, __logf(S), t);
        if (q > bv){ bv = q; bk = w*128 + kk; }
    }
    pc[w][lane] = c; ps[w][lane] = ss; pt[w][lane] = t; pb[w][lane] = bv; pkk[w][lane] = bk;
    __syncthreads();
    if (tid < 64){
        float C = 0.f, S2 = 0.f, T = 0.f, BV = -1.f; int BK = 0;
        #pragma unroll
        for (int g = 0; g < 8; ++g){
            C += pc[g][tid]; S2 += ps[g][tid]; T += pt[g][tid];
            float v = pb[g][tid]; int k2 = pkk[g][tid];
            if (v > BV || (v == BV && k2 < BK)){ BV = v; BK = k2; }
        }
        int nn = blockIdx.x*64 + tid;
        idx[nn] = BK;
        atomicAdd(&counts[BK], 1);
        // sum_k q*log(p+eps) ≈ T/C - log(S2)  (eps term negligible; tolerance huge)
        float lossn = T / C - __logf(S2);
        #pragma unroll
        for (int m = 1; m < 64; m <<= 1) lossn += __shfl_xor(lossn, m);
        if (tid == 0) atomicAdd(loss_acc, lossn);
    }
}

// ---------------- finalize ----------------
__global__ __launch_bounds__(256) void vq_finalize(const int* __restrict__ counts,
                                                   const float* __restrict__ loss_acc,
                                                   float* __restrict__ out){
    __shared__ int red[256];
    int t = threadIdx.x, c = 0;
    #pragma unroll
    for (int i = 0; i < 4; ++i) c += (counts[i*256 + t] > 0) ? 1 : 0;
    red[t] = c;
    __syncthreads();
    for (int s = 128; s > 0; s >>= 1){
        if (t < s) red[t] += red[t + s];
        __syncthreads();
    }
    if (t == 0){
        out[8388608] = -loss_acc[0] / 33554432.0f;
        out[8388609] = (float)red[0];
    }
}

// ---------------- z_q gather ----------------
__global__ __launch_bounds__(256) void vq_zq(const float* __restrict__ W, const int* __restrict__ idx,
                                             float* __restrict__ out){
    int gid = blockIdx.x*256 + threadIdx.x;
    int o = gid*4;
    int s = o & 4095, rem = o >> 12, c = rem & 255, b = rem >> 8;
    const int4 iv = *(const int4*)(idx + (b << 12) + s);
    float4 ov;
    ov.x = W[(size_t)iv.x*DDIM + c];
    ov.y = W[(size_t)iv.y*DDIM + c];
    ov.z = W[(size_t)iv.z*DDIM + c];
    ov.w = W[(size_t)iv.w*DDIM + c];
    *(float4*)(out + o) = ov;
}

extern "C" void kernel_launch(void* const* d_in, const int* in_sizes, int n_in,
                              void* d_out, int out_size, void* d_ws, size_t ws_size,
                              hipStream_t stream) {
    const float* z = (const float*)d_in[0];
    const float* W = (const float*)d_in[1];
    float* out = (float*)d_out;
    char* ws = (char*)d_ws;

    _Float16* ShT  = (_Float16*)(ws);                       // 67,108,864
    bf16x8*   Ab   = (bf16x8*)(ws + 67108864);              // 16,777,216
    bf16x8*   Bb   = (bf16x8*)(ws + 83886080);              //    524,288
    float*    invn = (float*)(ws + 84410368);               //    131,072
    float*    a1   = (float*)(ws + 84541440);               //      4,096
    float*    a2   = (float*)(ws + 84545536);
    float*    a3   = (float*)(ws + 84549632);
    float*    b1   = (float*)(ws + 84553728);               //    131,072
    float*    b2   = (float*)(ws + 84684800);               //    131,072
    int*      counts = (int*)(ws + 84815872);               //      4,096
    int*      idx    = (int*)(ws + 84819968);               //    131,072
    float*    loss   = (float*)(ws + 84951040);             //          4

    vq_init<<<1, 256, 0, stream>>>(counts, loss);
    vq_prepA<<<512, 256, 0, stream>>>(z, Ab, invn);
    vq_prepB<<<128, 256, 0, stream>>>(W, Bb);
    vq_gemmT<<<dim3(8, 256), 256, 0, stream>>>(Ab, Bb, invn, ShT);
    vq_row<<<1024, 256, 0, stream>>>(ShT, (const float*)nullptr, 0, a1);
    vq_col<<<512, 512, 0, stream>>>(ShT, a1, b1);
    vq_row<<<1024, 256, 0, stream>>>(ShT, b1, 1, a2);
    vq_col<<<512, 512, 0, stream>>>(ShT, a2, b2);
    vq_row<<<1024, 256, 0, stream>>>(ShT, b2, 1, a3);
    vq_final<<<512, 512, 0, stream>>>(ShT, a3, counts, idx, loss);
    vq_finalize<<<1, 256, 0, stream>>>(counts, loss, out);
    vq_zq<<<8192, 256, 0, stream>>>(W, idx, out);
}

// Round 5
// 240.109 us; speedup vs baseline: 1.7553x; 1.0610x over previous
//
#include <hip/hip_runtime.h>
#include <math.h>

typedef float    f32x4  __attribute__((ext_vector_type(4)));
typedef short    bf16x8 __attribute__((ext_vector_type(8)));
typedef _Float16 h16x8  __attribute__((ext_vector_type(8)));
typedef _Float16 h16x4  __attribute__((ext_vector_type(4)));
typedef _Float16 h16x2  __attribute__((ext_vector_type(2)));

#define NTOT 32768
#define KCB  1024
#define DDIM 256
#define SPAT 4096
#define ZB   1048576

__device__ __forceinline__ unsigned short f2bf(float f){
    unsigned u = __builtin_bit_cast(unsigned, f);
    u += 0x7fffu + ((u >> 16) & 1u);
    return (unsigned short)(u >> 16);
}

// ---------------- init: zero counts, R, loss ----------------
__global__ __launch_bounds__(256) void vq_init(int* __restrict__ counts, float* __restrict__ R,
                                               float* __restrict__ loss){
    int t = threadIdx.x;
    #pragma unroll
    for (int i = 0; i < 4; ++i) counts[i*256 + t] = 0;
    #pragma unroll
    for (int i = 0; i < 4; ++i) R[i*256 + t] = 0.0f;
    if (t == 0) loss[0] = 0.0f;
}

// ---------------- prepA: z -> fragment-major bf16 + invn ----------------
__global__ __launch_bounds__(256) void vq_prepA(const float* __restrict__ z, bf16x8* __restrict__ Ab,
                                                float* __restrict__ invn){
    __shared__ unsigned short lds[256][68];
    __shared__ float sbuf[4][64];
    int tid = threadIdx.x, lane = tid & 63, w = tid >> 6;
    int bid = blockIdx.x;
    int n0 = bid * 64, b = n0 >> 12, s0 = n0 & 4095;
    const float* zb = z + (size_t)b * ZB + s0;
    int col4 = tid & 15;
    float sq0 = 0.f, sq1 = 0.f, sq2 = 0.f, sq3 = 0.f;
    #pragma unroll
    for (int it = 0; it < 16; ++it){
        int c = it*16 + (tid >> 4);
        float4 v = *(const float4*)(zb + (size_t)c * SPAT + col4*4);
        sq0 += v.x*v.x; sq1 += v.y*v.y; sq2 += v.z*v.z; sq3 += v.w*v.w;
        unsigned long long pk = (unsigned long long)f2bf(v.x)
                              | ((unsigned long long)f2bf(v.y) << 16)
                              | ((unsigned long long)f2bf(v.z) << 32)
                              | ((unsigned long long)f2bf(v.w) << 48);
        *(unsigned long long*)&lds[c][col4*4] = pk;
    }
    sq0 += __shfl_xor(sq0,16); sq0 += __shfl_xor(sq0,32);
    sq1 += __shfl_xor(sq1,16); sq1 += __shfl_xor(sq1,32);
    sq2 += __shfl_xor(sq2,16); sq2 += __shfl_xor(sq2,32);
    sq3 += __shfl_xor(sq3,16); sq3 += __shfl_xor(sq3,32);
    if (lane < 16){
        sbuf[w][lane*4+0] = sq0; sbuf[w][lane*4+1] = sq1;
        sbuf[w][lane*4+2] = sq2; sbuf[w][lane*4+3] = sq3;
    }
    __syncthreads();
    if (tid < 64){
        float t = sbuf[0][tid] + sbuf[1][tid] + sbuf[2][tid] + sbuf[3][tid];
        invn[n0 + tid] = 1.0f / fmaxf(sqrtf(t), 1e-12f);
    }
    #pragma unroll
    for (int i = 0; i < 8; ++i){
        int x = i*4 + (tid >> 6);
        int cc = x & 7, g = x >> 3;
        int srow = g*16 + (lane & 15);
        int cbase = cc*32 + (lane >> 4)*8;
        bf16x8 fr;
        #pragma unroll
        for (int j = 0; j < 8; ++j) fr[j] = (short)lds[cbase + j][srow];
        Ab[(size_t)bid*2048 + i*256 + tid] = fr;
    }
}

// ---------------- prepB: W -> fragment-major bf16 ----------------
__global__ __launch_bounds__(256) void vq_prepB(const float* __restrict__ W, bf16x8* __restrict__ Bb){
    int slot = blockIdx.x*256 + threadIdx.x;
    int l = slot & 63, x = slot >> 6;
    int cc = x & 7, kg = x >> 3;
    int krow = kg*16 + (l & 15);
    int cbase = cc*32 + (l >> 4)*8;
    const float* wp = W + (size_t)krow*DDIM + cbase;
    float4 v0 = *(const float4*)wp, v1 = *(const float4*)(wp + 4);
    bf16x8 fr;
    fr[0] = (short)f2bf(v0.x); fr[1] = (short)f2bf(v0.y);
    fr[2] = (short)f2bf(v0.z); fr[3] = (short)f2bf(v0.w);
    fr[4] = (short)f2bf(v1.x); fr[5] = (short)f2bf(v1.y);
    fr[6] = (short)f2bf(v1.z); fr[7] = (short)f2bf(v1.w);
    Bb[slot] = fr;
}

// ---------------- MFMA GEMM: ShT[k][n] packed 8B stores; fused row-sum R[k] ----------------
__global__ __launch_bounds__(256) void vq_gemmT(const bf16x8* __restrict__ Ab, const bf16x8* __restrict__ Bb,
                                                const float* __restrict__ invn, _Float16* __restrict__ ShT,
                                                float* __restrict__ R){
    __shared__ float Rsh[128];
    int tid = threadIdx.x, lane = tid & 63, w = tid >> 6;
    int wm = w >> 1, wn = w & 1;
    int bk = blockIdx.x, bm = blockIdx.y;
    if (tid < 128) Rsh[tid] = 0.0f;
    const bf16x8* Ap = Ab + (size_t)(bm*8 + wm*4)*512 + lane;   // samples (rows)
    const bf16x8* Bp = Bb + (size_t)(bk*8 + wn*4)*512 + lane;   // codebook (cols)
    f32x4 zero4 = {0.f, 0.f, 0.f, 0.f};
    f32x4 acc[4][4];
    #pragma unroll
    for (int i = 0; i < 4; ++i)
        #pragma unroll
        for (int j = 0; j < 4; ++j) acc[i][j] = zero4;
    bf16x8 aF[2][4], bF[2][4];
    #pragma unroll
    for (int i = 0; i < 4; ++i){ aF[0][i] = Ap[i*512]; bF[0][i] = Bp[i*512]; }
    #pragma unroll
    for (int cc = 0; cc < 8; ++cc){
        int cur = cc & 1, nxt = cur ^ 1;
        if (cc < 7){
            #pragma unroll
            for (int i = 0; i < 4; ++i){
                aF[nxt][i] = Ap[i*512 + (cc+1)*64];
                bF[nxt][i] = Bp[i*512 + (cc+1)*64];
            }
        }
        #pragma unroll
        for (int i = 0; i < 4; ++i)
            #pragma unroll
            for (int j = 0; j < 4; ++j)
                acc[i][j] = __builtin_amdgcn_mfma_f32_16x16x32_bf16(aF[cur][i], bF[cur][j], acc[i][j], 0, 0, 0);
    }
    // rows = samples n, cols = codebook k; pack 4 consecutive n into one 8B store
    int rbase = bm*128 + wm*64 + (lane >> 4)*4;   // n
    int cbase = bk*128 + wn*64 + (lane & 15);     // k
    float invr[4][4];
    #pragma unroll
    for (int i = 0; i < 4; ++i)
        #pragma unroll
        for (int r = 0; r < 4; ++r) invr[i][r] = invn[rbase + i*16 + r];
    float cs[4] = {0.f, 0.f, 0.f, 0.f};
    #pragma unroll
    for (int j = 0; j < 4; ++j){
        size_t krow = (size_t)(cbase + j*16) * NTOT;
        #pragma unroll
        for (int i = 0; i < 4; ++i){
            h16x4 pk;
            #pragma unroll
            for (int rr = 0; rr < 4; ++rr){
                float val = acc[i][j][rr] * invr[i][rr];
                _Float16 vh = (_Float16)__expf(val * 10.0f);   // S = exp(L/T)
                float Sf = (float)vh;
                cs[j] = fmaf(Sf, Sf, cs[j]);                    // E = S^2
                pk[rr] = vh;
            }
            *(h16x4*)(ShT + krow + rbase + i*16) = pk;
        }
        cs[j] += __shfl_xor(cs[j], 16);
        cs[j] += __shfl_xor(cs[j], 32);
    }
    __syncthreads();
    if (lane < 16){
        #pragma unroll
        for (int j = 0; j < 4; ++j) atomicAdd(&Rsh[wn*64 + j*16 + lane], cs[j]);
    }
    __syncthreads();
    if (tid < 128) atomicAdd(&R[bk*128 + tid], Rsh[tid]);
}

// ---------------- row pass: a[k] = 1/(1024 * sum_n S^2 * b[n]) ----------------
__global__ __launch_bounds__(256) void vq_row(const _Float16* __restrict__ ShT, const float* __restrict__ bvec,
                                              float* __restrict__ aout){
    __shared__ float part[4];
    int tid = threadIdx.x, lane = tid & 63, w = tid >> 6;
    int k = blockIdx.x;
    const h16x8* Sp = (const h16x8*)(ShT + (size_t)k*NTOT) + w*1024 + lane;
    const float4* bp = (const float4*)bvec + w*2048 + lane*2;
    float acc = 0.f;
    #pragma unroll 4
    for (int it = 0; it < 16; ++it){
        h16x8 s = Sp[it*64];
        float4 b0 = bp[it*128];
        float4 b1 = bp[it*128 + 1];
        float f;
        f = (float)s[0]; acc = fmaf(f*f, b0.x, acc);
        f = (float)s[1]; acc = fmaf(f*f, b0.y, acc);
        f = (float)s[2]; acc = fmaf(f*f, b0.z, acc);
        f = (float)s[3]; acc = fmaf(f*f, b0.w, acc);
        f = (float)s[4]; acc = fmaf(f*f, b1.x, acc);
        f = (float)s[5]; acc = fmaf(f*f, b1.y, acc);
        f = (float)s[6]; acc = fmaf(f*f, b1.z, acc);
        f = (float)s[7]; acc = fmaf(f*f, b1.w, acc);
    }
    #pragma unroll
    for (int m = 1; m < 64; m <<= 1) acc += __shfl_xor(acc, m);
    if (lane == 0) part[w] = acc;
    __syncthreads();
    if (tid == 0) aout[k] = 1.0f / (1024.0f * (part[0] + part[1] + part[2] + part[3]));
}

// ---------------- col pass: b[n] = 1/(32768 * sum_k S^2 * a[k]); inv_mode: a=1/(1024*R) ----------------
__global__ __launch_bounds__(512) void vq_col(const _Float16* __restrict__ ShT, const float* __restrict__ vecin,
                                              int inv_mode, float* __restrict__ bout){
    __shared__ float ash[1024];
    __shared__ float part[8][128];
    int tid = threadIdx.x, lane = tid & 63, w = tid >> 6;
    float2 vv = ((const float2*)vecin)[tid];
    if (inv_mode){ vv.x = 1.0f/(1024.0f*vv.x); vv.y = 1.0f/(1024.0f*vv.y); }
    ((float2*)ash)[tid] = vv;
    __syncthreads();
    int n0 = blockIdx.x*128 + lane*2;
    const _Float16* Sp = ShT + (size_t)(w*128)*NTOT + n0;
    float c0 = 0.f, c1 = 0.f;
    #pragma unroll 8
    for (int kk = 0; kk < 128; ++kk){
        h16x2 s = *(const h16x2*)(Sp + (size_t)kk*NTOT);
        float a = ash[w*128 + kk];
        float f0 = (float)s[0]; c0 = fmaf(f0*f0, a, c0);
        float f1 = (float)s[1]; c1 = fmaf(f1*f1, a, c1);
    }
    part[w][lane*2] = c0; part[w][lane*2+1] = c1;
    __syncthreads();
    if (tid < 128){
        float t = 0.f;
        #pragma unroll
        for (int g = 0; g < 8; ++g) t += part[g][tid];
        bout[blockIdx.x*128 + tid] = 1.0f / (32768.0f * t);
    }
}

// ---------------- final: argmax, counts, loss ----------------
__global__ __launch_bounds__(512) void vq_final(const _Float16* __restrict__ ShT, const float* __restrict__ avec,
                                                int* __restrict__ counts, int* __restrict__ idx,
                                                float* __restrict__ loss_acc){
    __shared__ float ash[1024];
    __shared__ float pc[8][128], ps[8][128], pt[8][128], pb[8][128];
    __shared__ int   pkk[8][128];
    int tid = threadIdx.x, lane = tid & 63, w = tid >> 6;
    ((float2*)ash)[tid] = ((const float2*)avec)[tid];
    __syncthreads();
    int n0 = blockIdx.x*128 + lane*2;
    const _Float16* Sp = ShT + (size_t)(w*128)*NTOT + n0;
    float c0=0.f, c1=0.f, ss0=0.f, ss1=0.f, t0=0.f, t1=0.f, bv0=-1.f, bv1=-1.f;
    int bk0 = 0, bk1 = 0;
    #pragma unroll 4
    for (int kk = 0; kk < 128; ++kk){
        h16x2 s = *(const h16x2*)(Sp + (size_t)kk*NTOT);
        float a = ash[w*128 + kk];
        float f0 = (float)s[0], f1 = (float)s[1];
        float q0 = f0*f0*a, q1 = f1*f1*a;
        c0 += q0; c1 += q1; ss0 += f0; ss1 += f1;
        t0 = fmaf(q0, __logf(f0), t0);
        t1 = fmaf(q1, __logf(f1), t1);
        if (q0 > bv0){ bv0 = q0; bk0 = w*128 + kk; }
        if (q1 > bv1){ bv1 = q1; bk1 = w*128 + kk; }
    }
    pc[w][lane*2] = c0;  pc[w][lane*2+1] = c1;
    ps[w][lane*2] = ss0; ps[w][lane*2+1] = ss1;
    pt[w][lane*2] = t0;  pt[w][lane*2+1] = t1;
    pb[w][lane*2] = bv0; pb[w][lane*2+1] = bv1;
    pkk[w][lane*2] = bk0; pkk[w][lane*2+1] = bk1;
    __syncthreads();
    if (tid < 128){
        float C = 0.f, S2 = 0.f, T = 0.f, BV = -1.f; int BK = 0;
        #pragma unroll
        for (int g = 0; g < 8; ++g){
            C += pc[g][tid]; S2 += ps[g][tid]; T += pt[g][tid];
            float v = pb[g][tid]; int k2 = pkk[g][tid];
            if (v > BV || (v == BV && k2 < BK)){ BV = v; BK = k2; }
        }
        int nn = blockIdx.x*128 + tid;
        idx[nn] = BK;
        atomicAdd(&counts[BK], 1);
        // sum_k q*log(p+eps) ≈ T/C - log(S2)
        float lossn = T / C - __logf(S2);
        #pragma unroll
        for (int m = 1; m < 64; m <<= 1) lossn += __shfl_xor(lossn, m);
        if ((tid & 63) == 0) atomicAdd(loss_acc, lossn);
    }
}

// ---------------- finalize ----------------
__global__ __launch_bounds__(256) void vq_finalize(const int* __restrict__ counts,
                                                   const float* __restrict__ loss_acc,
                                                   float* __restrict__ out){
    __shared__ int red[256];
    int t = threadIdx.x, c = 0;
    #pragma unroll
    for (int i = 0; i < 4; ++i) c += (counts[i*256 + t] > 0) ? 1 : 0;
    red[t] = c;
    __syncthreads();
    for (int s = 128; s > 0; s >>= 1){
        if (t < s) red[t] += red[t + s];
        __syncthreads();
    }
    if (t == 0){
        out[8388608] = -loss_acc[0] / 33554432.0f;
        out[8388609] = (float)red[0];
    }
}

// ---------------- z_q gather ----------------
__global__ __launch_bounds__(256) void vq_zq(const float* __restrict__ W, const int* __restrict__ idx,
                                             float* __restrict__ out){
    int gid = blockIdx.x*256 + threadIdx.x;
    int o = gid*4;
    int s = o & 4095, rem = o >> 12, c = rem & 255, b = rem >> 8;
    const int4 iv = *(const int4*)(idx + (b << 12) + s);
    float4 ov;
    ov.x = W[(size_t)iv.x*DDIM + c];
    ov.y = W[(size_t)iv.y*DDIM + c];
    ov.z = W[(size_t)iv.z*DDIM + c];
    ov.w = W[(size_t)iv.w*DDIM + c];
    *(float4*)(out + o) = ov;
}

extern "C" void kernel_launch(void* const* d_in, const int* in_sizes, int n_in,
                              void* d_out, int out_size, void* d_ws, size_t ws_size,
                              hipStream_t stream) {
    const float* z = (const float*)d_in[0];
    const float* W = (const float*)d_in[1];
    float* out = (float*)d_out;
    char* ws = (char*)d_ws;

    _Float16* ShT  = (_Float16*)(ws);                       // 67,108,864
    bf16x8*   Ab   = (bf16x8*)(ws + 67108864);              // 16,777,216
    bf16x8*   Bb   = (bf16x8*)(ws + 83886080);              //    524,288
    float*    invn = (float*)(ws + 84410368);               //    131,072
    float*    R    = (float*)(ws + 84541440);               //      4,096
    float*    a2   = (float*)(ws + 84545536);
    float*    a3   = (float*)(ws + 84549632);
    float*    b1   = (float*)(ws + 84553728);               //    131,072
    float*    b2   = (float*)(ws + 84684800);               //    131,072
    int*      counts = (int*)(ws + 84815872);               //      4,096
    int*      idx    = (int*)(ws + 84819968);               //    131,072
    float*    loss   = (float*)(ws + 84951040);             //          4

    vq_init<<<1, 256, 0, stream>>>(counts, R, loss);
    vq_prepA<<<512, 256, 0, stream>>>(z, Ab, invn);
    vq_prepB<<<128, 256, 0, stream>>>(W, Bb);
    vq_gemmT<<<dim3(8, 256), 256, 0, stream>>>(Ab, Bb, invn, ShT, R);
    vq_col<<<256, 512, 0, stream>>>(ShT, R, 1, b1);
    vq_row<<<1024, 256, 0, stream>>>(ShT, b1, a2);
    vq_col<<<256, 512, 0, stream>>>(ShT, a2, 0, b2);
    vq_row<<<1024, 256, 0, stream>>>(ShT, b2, a3);
    vq_final<<<256, 512, 0, stream>>>(ShT, a3, counts, idx, loss);
    vq_finalize<<<1, 256, 0, stream>>>(counts, loss, out);
    vq_zq<<<8192, 256, 0, stream>>>(W, idx, out);
}